// Round 4
// baseline (13.452 us; speedup 1.0000x reference)
//
#include <hip/hip_runtime.h>

#define L_     512
#define GAMMA_ 0.1f

typedef _Float16 h2  __attribute__((ext_vector_type(2)));
typedef _Float16 h8  __attribute__((ext_vector_type(8)));
typedef float    f32x4 __attribute__((ext_vector_type(4)));

struct alignas(16) H8 { h2 h[4]; };

#if __has_builtin(__builtin_amdgcn_fdot2)
#define DOT2(a,b,c) __builtin_amdgcn_fdot2((a),(b),(c),false)
#else
__device__ __forceinline__ float DOT2(h2 a, h2 b, float c) {
    return fmaf((float)a.x,(float)b.x, fmaf((float)a.y,(float)b.y,c));
}
#endif

// 256 blocks (1/CU), 256 threads (4 waves, 1 wave/SIMD). Block owns 16 rows
// (8 batches x 2 l). Embedding computed by ONE mfma per 16-dim tile:
//   A[16 rows][32 k] = conv-window(21) + marks(4) + zero pad, f16 (1 KB LDS)
//   B[32 k][512 d]   = W_token/W_time transposed f16 B-frag layout (32 KB LDS,
//                      staged via fully-coalesced float4 loads)
// pe(l,d) added in-register after the MFMA (fast trig), result -> xA (16 KB).
// Phase 3 (RBF): sv B-fragments gathered DIRECTLY from global as f32x4 pairs
// (hoisted to kernel top; latency hides under staging+embedding), cvt f16,
// 16 mfma; snorm accumulated in-register from the same f32 data (no LDS).
__global__ __launch_bounds__(256, 1) void fused_model_kernel(
    const float* __restrict__ x_enc,    // [8,512,7]
    const float* __restrict__ x_mark,   // [8,512,4]
    const float* __restrict__ W_token,  // [512,7,3]
    const float* __restrict__ W_time,   // [512,4]
    const float* __restrict__ sv,       // [50,512]
    const float* __restrict__ alphas,   // [50]
    const float* __restrict__ bias,     // [7]
    float* __restrict__ out)            // [8,512,7]
{
    __shared__ h8 Wb8[32*64];     // 32 KB: slot = dtile*64 + (d&15)*4 + g
    __shared__ h8 xA8[64*16];     // 16 KB: slot = kblk*16 + row
    __shared__ h8 Axw[16*4];      //  1 KB: slot = row*4 + g
    __shared__ float xin[224];    // [b][j=0..3][c] conv window (l0-1 .. l0+2)
    __shared__ float xmk[64];     // [b][il][f]
    __shared__ float xnL[64], xnF[16], alph[64], part[64];

    const int t    = threadIdx.x;
    const int l0   = blockIdx.x * 2;
    const int w    = t >> 6;
    const int lane = t & 63;
    const int q    = lane & 15;
    const int g    = lane >> 4;

    // ---- hoisted sv gathers: lane (q,g) needs sv[s=w*16+q][k = (ks*4+g)*8 ..+7]
    const int s     = w*16 + q;
    const int s_eff = (s < 50) ? s : 49;
    const f32x4* svp = (const f32x4*)(sv + s_eff * 512);
    f32x4 ga[16], gb[16];
#pragma unroll
    for (int ks = 0; ks < 16; ++ks) {
        ga[ks] = svp[(ks*4 + g)*2];
        gb[ks] = svp[(ks*4 + g)*2 + 1];
    }

    // ---- stage W (coalesced float4) -> f16 B-frag layout in LDS ----
    // half index for (d, k): (d>>4)*512 + (d&15)*32 + k
    _Float16* Wbh = (_Float16*)Wb8;
    const f32x4* wt4 = (const f32x4*)W_token;      // 2688 float4s
#pragma unroll
    for (int kk2 = 0; kk2 < 11; ++kk2) {
        int i4 = t + kk2*256;
        if (i4 < 2688) {
            f32x4 v = wt4[i4];
            int f0 = i4*4;
#pragma unroll
            for (int e = 0; e < 4; ++e) {
                int f = f0 + e;
                int d = f / 21;
                int k = f - d*21;
                float x = (e==0) ? v.x : (e==1) ? v.y : (e==2) ? v.z : v.w;
                Wbh[(d>>4)*512 + (d&15)*32 + k] = (_Float16)x;
            }
        }
    }
    const f32x4* wm4 = (const f32x4*)W_time;       // 512 float4s
#pragma unroll
    for (int kk2 = 0; kk2 < 2; ++kk2) {
        int i4 = t + kk2*256;
        f32x4 v = wm4[i4];
        int f0 = i4*4;
#pragma unroll
        for (int e = 0; e < 4; ++e) {
            int f = f0 + e;
            int d = f >> 2;
            int k = 21 + (f & 3);
            float x = (e==0) ? v.x : (e==1) ? v.y : (e==2) ? v.z : v.w;
            Wbh[(d>>4)*512 + (d&15)*32 + k] = (_Float16)x;
        }
    }
#pragma unroll
    for (int dd = 0; dd < 2; ++dd) {               // zero pad k = 25..31
        int d = t + dd*256;
        int base = (d>>4)*512 + (d&15)*32;
#pragma unroll
        for (int k = 25; k < 32; ++k) Wbh[base + k] = (_Float16)0.f;
    }

    // ---- stage conv window, marks, alphas ----
    if (t < 224) {
        int b = t/28, rem = t%28, j = rem/7, c = rem%7;
        int gl = (l0 - 1 + j) & (L_ - 1);
        xin[t] = x_enc[(b*L_ + gl)*7 + c];
    }
    if (t < 64) {
        int b = t>>3, il = (t>>2)&1, f = t&3;
        xmk[t] = x_mark[(b*L_ + l0 + il)*4 + f];
    }
    if (t < 64) alph[t] = (t < 50) ? alphas[t] : 0.f;
    __syncthreads();   // B1: xin/xmk ready (Wb also done)

    // ---- build A fragment: A[row][k], k<21 conv, 21..24 marks, else 0 ----
    {
        int r = t >> 4, p = t & 15;
        int il = r >> 3, b = r & 7;
        float v[2];
#pragma unroll
        for (int e = 0; e < 2; ++e) {
            int k = 2*p + e;
            float x;
            if (k < 21) { int c = k/3, kk = k - c*3; x = xin[b*28 + (il+kk)*7 + c]; }
            else if (k < 25) x = xmk[(b*2 + il)*4 + (k - 21)];
            else x = 0.f;
            v[e] = x;
        }
        ((h2*)Axw)[r*16 + p] = h2{(_Float16)v[0], (_Float16)v[1]};
    }
    __syncthreads();   // B2: A ready

    // ---- embedding MFMA: wave w -> dtiles w*8 .. w*8+7; C[r][d] + pe -> xA ----
    {
        h8 av4 = Axw[q*4 + g];
        const float C1 = -0.017988946039016654f;   // -ln(10000)/512
        const int il = g >> 1;                     // rows g*4..g*4+3 share il
#pragma unroll
        for (int tt = 0; tt < 8; ++tt) {
            int dt = w*8 + tt;
            h8 bw = Wb8[dt*64 + q*4 + g];
            f32x4 c4 = {0.f, 0.f, 0.f, 0.f};
            c4 = __builtin_amdgcn_mfma_f32_16x16x32_f16(av4, bw, c4, 0, 0, 0);
            int d = dt*16 + q;
            float dv  = __expf(C1 * (float)(d & ~1));
            float ang = (float)(l0 + il) * dv;
            float pe  = (d & 1) ? __cosf(ang) : __sinf(ang);
#pragma unroll
            for (int i = 0; i < 4; ++i) {
                int r = g*4 + i;
                ((_Float16*)xA8)[(d>>3)*128 + r*8 + (d&7)] = (_Float16)(c4[i] + pe);
            }
        }
    }
    __syncthreads();   // B3: xA ready

    // ---- phase 3: 16 mfma over K=512; snorm in-register from f32 gathers ----
    float ssq = 0.f;
    f32x4 acc = {0.f, 0.f, 0.f, 0.f};
#pragma unroll
    for (int ks = 0; ks < 16; ++ks) {
        f32x4 a = ga[ks], b2 = gb[ks];
        h8 bv;
        bv[0]=(_Float16)a.x;  bv[1]=(_Float16)a.y;  bv[2]=(_Float16)a.z;  bv[3]=(_Float16)a.w;
        bv[4]=(_Float16)b2.x; bv[5]=(_Float16)b2.y; bv[6]=(_Float16)b2.z; bv[7]=(_Float16)b2.w;
        ssq = fmaf(a.x,a.x,ssq);  ssq = fmaf(a.y,a.y,ssq);
        ssq = fmaf(a.z,a.z,ssq);  ssq = fmaf(a.w,a.w,ssq);
        ssq = fmaf(b2.x,b2.x,ssq); ssq = fmaf(b2.y,b2.y,ssq);
        ssq = fmaf(b2.z,b2.z,ssq); ssq = fmaf(b2.w,b2.w,ssq);
        h8 av = xA8[(ks*4 + g)*16 + q];
        acc = __builtin_amdgcn_mfma_f32_16x16x32_f16(av, bv, acc, 0, 0, 0);
    }
    ssq += __shfl_xor(ssq, 16, 64);
    ssq += __shfl_xor(ssq, 32, 64);     // full ||sv_s||^2 (lane's sv)

    // ---- xnorm: row q partial over kblks w*16..w*16+15, reduce over g ----
    {
        float xsq = 0.f;
#pragma unroll
        for (int i = 0; i < 4; ++i) {
            H8 v = __builtin_bit_cast(H8, xA8[(w*16 + g*4 + i)*16 + q]);
            xsq = DOT2(v.h[0],v.h[0],xsq); xsq = DOT2(v.h[1],v.h[1],xsq);
            xsq = DOT2(v.h[2],v.h[2],xsq); xsq = DOT2(v.h[3],v.h[3],xsq);
        }
        xsq += __shfl_xor(xsq, 16, 64);
        xsq += __shfl_xor(xsq, 32, 64);
        if (g == 0) xnL[w*16 + q] = xsq;
    }
    __syncthreads();   // B4
    if (t < 16) xnF[t] = xnL[t] + xnL[16+t] + xnL[32+t] + xnL[48+t];
    __syncthreads();   // B5

    // ---- epilogue: dist^2 -> alpha*exp -> sum over this wave's 16 svs ----
    {
        float alpha = alph[s];
        bool valid = (s < 50);
        float vals[4];
#pragma unroll
        for (int i = 0; i < 4; ++i) {
            int row = g*4 + i;
            float d2 = xnF[row] + ssq - 2.f*acc[i];
            float vv = alpha * __expf(-GAMMA_ * d2);
            vals[i] = valid ? vv : 0.f;
#pragma unroll
            for (int off = 1; off < 16; off <<= 1)
                vals[i] += __shfl_xor(vals[i], off, 64);
        }
        if (q == 0) {
#pragma unroll
            for (int i = 0; i < 4; ++i) part[w*16 + g*4 + i] = vals[i];
        }
    }
    __syncthreads();   // B6

    if (t < 112) {
        int r = t / 7, c = t % 7;
        int b = r & 7, il = r >> 3;
        out[(b*L_ + l0 + il)*7 + c] =
            part[r] + part[16+r] + part[32+r] + part[48+r] + bias[c];
    }
}

extern "C" void kernel_launch(void* const* d_in, const int* in_sizes, int n_in,
                              void* d_out, int out_size, void* d_ws, size_t ws_size,
                              hipStream_t stream) {
    (void)d_ws; (void)ws_size; (void)in_sizes; (void)n_in;
    const float* x_enc      = (const float*)d_in[0];
    const float* x_mark_enc = (const float*)d_in[1];
    // d_in[2] (x_dec), d_in[3] (x_mark_dec) unused by the reference.
    const float* W_token    = (const float*)d_in[4];
    const float* W_time     = (const float*)d_in[5];
    const float* sv         = (const float*)d_in[6];
    const float* alphas     = (const float*)d_in[7];
    const float* bias       = (const float*)d_in[8];
    float* out = (float*)d_out;

    fused_model_kernel<<<dim3(L_ / 2), dim3(256), 0, stream>>>(
        x_enc, x_mark_enc, W_token, W_time, sv, alphas, bias, out);
}